// Round 2
// baseline (901.577 us; speedup 1.0000x reference)
//
#include <hip/hip_runtime.h>
#include <math.h>

#define TS  16          // pixel tile edge
#define HS  18          // tile + halo
#define CIN 64
#define OC  64
#define K2  9
#define HW  128

__global__ __launch_bounds__(256, 1)
void dyfconv_kernel(const float* __restrict__ x,      // (B, C, H, W)
                    const float* __restrict__ weight, // (C, OC, 3, 3)
                    const float* __restrict__ bias,   // (OC,)
                    const float* __restrict__ op_w,   // (81, 9)
                    const float* __restrict__ op_b,   // (81,)
                    float* __restrict__ out)          // (B, OC, H, W)
{
    __shared__ float sx[CIN][HS * HS];   // 64 * 324 * 4 = 82944 B
    __shared__ float sT[HS * HS];        // 1296 B  (channel square-sum)

    const int tid = threadIdx.x;
    const int b  = blockIdx.z;
    const int h0 = blockIdx.y * TS;
    const int w0 = blockIdx.x * TS;

    const float* __restrict__ xb = x + (size_t)b * CIN * HW * HW;

    // ---- stage x tile (halo, zero-padded) ----
    for (int i = tid; i < CIN * HS * HS; i += 256) {
        int c  = i / (HS * HS);
        int r  = i - c * (HS * HS);
        int yy = r / HS;
        int xx = r - yy * HS;
        int gy = h0 - 1 + yy;
        int gx = w0 - 1 + xx;
        float v = 0.f;
        if ((unsigned)gy < HW && (unsigned)gx < HW)
            v = xb[c * HW * HW + gy * HW + gx];
        sx[c][r] = v;
    }
    __syncthreads();

    // ---- channel square-sum map T (norm^2 for every tap position) ----
    for (int i = tid; i < HS * HS; i += 256) {
        float s = 0.f;
        #pragma unroll 8
        for (int c = 0; c < CIN; ++c) { float v = sx[c][i]; s += v * v; }
        sT[i] = s;
    }
    __syncthreads();

    const int tx = tid & 15, ty = tid >> 4;
    const int p0 = (ty + 1) * HS + (tx + 1);   // center position in halo coords

    // ---- patch norms ----
    float nrm[K2];
    #pragma unroll
    for (int j = 0; j < K2; ++j) {
        const int dy = j / 3 - 1, dx = j % 3 - 1;
        nrm[j] = sqrtf(sT[p0 + dy * HS + dx]);
    }

    // ---- dynamic operator: op[j][k] = tanh(n . op_w[j*9+k] + op_b) ----
    float op[K2 * K2];
    #pragma unroll
    for (int m = 0; m < K2 * K2; ++m) {
        float a = op_b[m];
        #pragma unroll
        for (int j = 0; j < K2; ++j) a += nrm[j] * op_w[m * K2 + j];
        op[m] = tanhf(a);
    }

    // ---- main contraction ----
    float acc[OC];
    #pragma unroll
    for (int o = 0; o < OC; ++o) acc[o] = 0.f;

    #pragma unroll 1
    for (int c = 0; c < CIN; ++c) {
        float xu[K2];
        #pragma unroll
        for (int j = 0; j < K2; ++j) {
            const int dy = j / 3 - 1, dx = j % 3 - 1;
            xu[j] = sx[c][p0 + dy * HS + dx];
        }
        float y[K2];
        #pragma unroll
        for (int k = 0; k < K2; ++k) {
            float s = xu[k];
            #pragma unroll
            for (int j = 0; j < K2; ++j) s += xu[j] * op[j * K2 + k];
            y[k] = s;
        }
        // weight slice for this c is 576 contiguous floats -> scalar loads
        const float* __restrict__ wc = weight + (size_t)c * OC * K2;
        #pragma unroll
        for (int o = 0; o < OC; ++o) {
            float s = acc[o];
            #pragma unroll
            for (int k = 0; k < K2; ++k) s += y[k] * wc[o * K2 + k];
            acc[o] = s;
        }
    }

    // ---- epilogue: bias + store ----
    const int h = h0 + ty, w = w0 + tx;
    float* __restrict__ ob = out + (size_t)b * OC * HW * HW + h * HW + w;
    #pragma unroll
    for (int o = 0; o < OC; ++o)
        ob[o * HW * HW] = acc[o] + bias[o];
}

extern "C" void kernel_launch(void* const* d_in, const int* in_sizes, int n_in,
                              void* d_out, int out_size, void* d_ws, size_t ws_size,
                              hipStream_t stream) {
    const float* x      = (const float*)d_in[0];
    const float* weight = (const float*)d_in[1];
    const float* bias   = (const float*)d_in[2];
    const float* op_w   = (const float*)d_in[3];
    const float* op_b   = (const float*)d_in[4];
    float* out = (float*)d_out;

    dim3 grid(HW / TS, HW / TS, 8);   // 8 x 8 x 8 = 512 blocks
    dim3 block(256);
    dyfconv_kernel<<<grid, block, 0, stream>>>(x, weight, bias, op_w, op_b, out);
}

// Round 3
// 262.661 us; speedup vs baseline: 3.4325x; 3.4325x over previous
//
#include <hip/hip_runtime.h>
#include <math.h>
#include <stdint.h>

#define HW   128
#define CIN  64
#define OC   64
#define TW   16          // pixel tile width
#define TH   4           // pixel tile height
#define HLW  18          // halo width  (TW+2)
#define HLH  6           // halo height (TH+2)
#define HLN  (HLW*HLH)   // 108 halo positions
#define NPX  (TW*TH)     // 64 pixels per block
#define K2   9
#define KTOT (CIN*K2)    // 576
#define ZROW 584         // zt row stride (ushorts): 1168 B, 16B-aligned, bank-spread

typedef __bf16 bf16x8 __attribute__((ext_vector_type(8)));
typedef float  f32x4  __attribute__((ext_vector_type(4)));

// ---- prep: WT[o][kt*64 + c] = bf16(weight[c][o][kt]) ----
__global__ void prep_weight(const float* __restrict__ w, ushort* __restrict__ wt) {
    int n = blockIdx.x * 256 + threadIdx.x;        // 0 .. 36863
    int o = n / KTOT;
    int r = n - o * KTOT;
    int kt = r >> 6;                               // r / 64
    int c  = r & 63;
    union { float f; uint32_t u; } x;
    x.f = w[(c * OC + o) * K2 + kt];
    wt[n] = (ushort)((x.u + 0x7FFF + ((x.u >> 16) & 1)) >> 16);   // RNE
}

__global__ __launch_bounds__(256, 1)
void dyf_main(const float* __restrict__ x,
              const float* __restrict__ bias,
              const float* __restrict__ op_w,
              const float* __restrict__ op_b,
              const ushort* __restrict__ wt,
              float* __restrict__ out)
{
    __shared__ float  sx[CIN][HLN];     // 27648 B
    __shared__ float  sT[HLN];          //   432 B
    __shared__ float  sop[NPX][81];     // 20736 B
    __shared__ ushort zt[NPX * ZROW];   // 74752 B   (total ~123.5 KB)

    const int tid  = threadIdx.x;
    const int lane = tid & 63;
    const int wv   = tid >> 6;
    const int b    = blockIdx.z;
    const int h0   = blockIdx.y * TH;
    const int w0   = blockIdx.x * TW;

    // ---- A-fragment preload (overlaps all later phases).
    // Wave wv owns o in [16*wv, 16*wv+16). Slot convention: k = s*32 + g*8 + i.
    bf16x8 areg[18];
    {
        const ushort* ap = wt + (wv * 16 + (lane & 15)) * KTOT + ((lane >> 4) * 8);
        #pragma unroll
        for (int s = 0; s < 18; ++s)
            areg[s] = *reinterpret_cast<const bf16x8*>(ap + s * 32);
    }

    // ---- stage x tile + halo (zero-padded) ----
    const float* __restrict__ xb = x + (size_t)b * CIN * HW * HW;
    #pragma unroll
    for (int it = 0; it < 27; ++it) {              // 27*256 = 6912 = CIN*HLN
        int i  = tid + it * 256;
        int c  = i / HLN;
        int r  = i - c * HLN;
        int hy = r / HLW;
        int hx = r - hy * HLW;
        int gy = h0 - 1 + hy;
        int gx = w0 - 1 + hx;
        float v = 0.f;
        if ((unsigned)gy < HW && (unsigned)gx < HW)
            v = xb[c * HW * HW + gy * HW + gx];
        sx[c][r] = v;
    }
    __syncthreads();

    // ---- T: per-position channel square-sum ----
    if (tid < HLN) {
        float s = 0.f;
        #pragma unroll 16
        for (int c = 0; c < CIN; ++c) { float v = sx[c][tid]; s += v * v; }
        sT[tid] = s;
    }
    __syncthreads();

    // ---- per-pixel norms + dynamic operator -> sop (f32) ----
    {
        const int px  = tid >> 2;                  // 0..63
        const int q   = tid & 3;
        const int py  = px >> 4, pxx = px & 15;
        float nrm[9];
        #pragma unroll
        for (int j = 0; j < 9; ++j)
            nrm[j] = sqrtf(sT[(py + j / 3) * HLW + pxx + (j % 3)]);
        const int m0   = q * 20;
        const int mcnt = (q == 3) ? 21 : 20;
        for (int mm = 0; mm < mcnt; ++mm) {
            int m = m0 + mm;
            float a = op_b[m];
            #pragma unroll
            for (int j = 0; j < 9; ++j) a += nrm[j] * op_w[m * 9 + j];
            sop[px][m] = tanhf(a);
        }
    }
    __syncthreads();

    // ---- Z phase: z[px][kt*64+c] = xu[kt] + sum_j xu[j]*op[j][kt]  (bf16) ----
    {
        const int px  = tid >> 2;
        const int cg  = tid & 3;                   // c-group of 16
        const int py  = px >> 4, pxx = px & 15;
        float opr[81];
        #pragma unroll
        for (int m = 0; m < 81; ++m) opr[m] = sop[px][m];

        uint32_t ybuf[9][8];
        #pragma unroll
        for (int cp = 0; cp < 8; ++cp) {           // pairs of c
            float y0[9], y1[9];
            {
                const int c = cg * 16 + cp * 2;
                float xu[9];
                #pragma unroll
                for (int j = 0; j < 9; ++j)
                    xu[j] = sx[c][(py + j / 3) * HLW + pxx + (j % 3)];
                #pragma unroll
                for (int k = 0; k < 9; ++k) {
                    float s = xu[k];
                    #pragma unroll
                    for (int j = 0; j < 9; ++j) s += xu[j] * opr[j * 9 + k];
                    y0[k] = s;
                }
            }
            {
                const int c = cg * 16 + cp * 2 + 1;
                float xu[9];
                #pragma unroll
                for (int j = 0; j < 9; ++j)
                    xu[j] = sx[c][(py + j / 3) * HLW + pxx + (j % 3)];
                #pragma unroll
                for (int k = 0; k < 9; ++k) {
                    float s = xu[k];
                    #pragma unroll
                    for (int j = 0; j < 9; ++j) s += xu[j] * opr[j * 9 + k];
                    y1[k] = s;
                }
            }
            #pragma unroll
            for (int k = 0; k < 9; ++k) {
                uint32_t r;
                asm("v_cvt_pk_bf16_f32 %0, %1, %2" : "=v"(r) : "v"(y0[k]), "v"(y1[k]));
                ybuf[k][cp] = r;                   // low half = even c
            }
        }
        #pragma unroll
        for (int k = 0; k < 9; ++k) {
            uint4* dst = reinterpret_cast<uint4*>(&zt[px * ZROW + k * 64 + cg * 16]);
            dst[0] = make_uint4(ybuf[k][0], ybuf[k][1], ybuf[k][2], ybuf[k][3]);
            dst[1] = make_uint4(ybuf[k][4], ybuf[k][5], ybuf[k][6], ybuf[k][7]);
        }
    }
    __syncthreads();

    // ---- MFMA: out[o, px] = sum_ck WT[o][ck] * z[px][ck] ----
    {
        f32x4 acc[4];
        #pragma unroll
        for (int nf = 0; nf < 4; ++nf) acc[nf] = f32x4{0.f, 0.f, 0.f, 0.f};

        const int bl = lane & 15;
        const int g8 = (lane >> 4) * 8;
        #pragma unroll
        for (int s = 0; s < 18; ++s) {
            #pragma unroll
            for (int nf = 0; nf < 4; ++nf) {
                const ushort* bp = &zt[(nf * 16 + bl) * ZROW + s * 32 + g8];
                bf16x8 bfr = *reinterpret_cast<const bf16x8*>(bp);
                acc[nf] = __builtin_amdgcn_mfma_f32_16x16x32_bf16(areg[s], bfr, acc[nf], 0, 0, 0);
            }
        }
        // D: row m = o = wv*16 + (lane>>4)*4 + i ; col n = px = nf*16 + bl
        // px tile row py = nf, x = bl  -> 16-lane contiguous 64B store segments
        #pragma unroll
        for (int nf = 0; nf < 4; ++nf) {
            #pragma unroll
            for (int i = 0; i < 4; ++i) {
                const int o = wv * 16 + (lane >> 4) * 4 + i;
                out[(((size_t)b * OC + o) * HW + (h0 + nf)) * HW + w0 + bl]
                    = acc[nf][i] + bias[o];
            }
        }
    }
}

extern "C" void kernel_launch(void* const* d_in, const int* in_sizes, int n_in,
                              void* d_out, int out_size, void* d_ws, size_t ws_size,
                              hipStream_t stream) {
    const float* x      = (const float*)d_in[0];
    const float* weight = (const float*)d_in[1];
    const float* bias   = (const float*)d_in[2];
    const float* op_w   = (const float*)d_in[3];
    const float* op_b   = (const float*)d_in[4];
    float*  out = (float*)d_out;
    ushort* wt  = (ushort*)d_ws;                   // 36864 ushorts = 73728 B

    prep_weight<<<dim3((OC * KTOT) / 256), dim3(256), 0, stream>>>(weight, wt);

    dim3 grid(HW / TW, HW / TH, 8);                // (8, 32, 8) = 2048 blocks
    dyf_main<<<grid, dim3(256), 0, stream>>>(x, bias, op_w, op_b, wt, out);
}

// Round 4
// 200.056 us; speedup vs baseline: 4.5066x; 1.3129x over previous
//
#include <hip/hip_runtime.h>
#include <math.h>
#include <stdint.h>

#define HW   128
#define CIN  64
#define OC   64
#define TW   16          // pixel tile width
#define TH   4           // pixel tile height
#define HLW  18          // halo width  (TW+2)
#define HLH  6           // halo height (TH+2)
#define HLN  (HLW*HLH)   // 108 halo positions
#define SXR  109         // sx row stride (floats) -> 2-way banks in Z phase
#define NPX  (TW*TH)     // 64 pixels per block
#define K2   9
#define KTOT (CIN*K2)    // 576
#define ZROW 584         // zt row stride (ushorts) = 1168 B, 16B aligned

typedef __bf16 bf16x8 __attribute__((ext_vector_type(8)));
typedef float  f32x4  __attribute__((ext_vector_type(4)));

__device__ __forceinline__ ushort f32_to_bf16_rne(float f) {
    union { float f; uint32_t u; } x; x.f = f;
    return (ushort)((x.u + 0x7FFF + ((x.u >> 16) & 1)) >> 16);
}
__device__ __forceinline__ float bf16u_to_f32(ushort u) {
    union { uint32_t u; float f; } x; x.u = ((uint32_t)u) << 16;
    return x.f;
}

// ---- prep: WT[o][kt*64 + c] = bf16(weight[c][o][kt]) ----
__global__ void prep_weight(const float* __restrict__ w, ushort* __restrict__ wt) {
    int n = blockIdx.x * 256 + threadIdx.x;        // 0 .. 36863
    int o = n / KTOT;
    int r = n - o * KTOT;
    int kt = r >> 6;
    int c  = r & 63;
    wt[n] = f32_to_bf16_rne(w[(c * OC + o) * K2 + kt]);
}

__global__ __launch_bounds__(256, 2)
void dyf_main(const float* __restrict__ x,
              const float* __restrict__ bias,
              const float* __restrict__ op_w,
              const float* __restrict__ op_b,
              const ushort* __restrict__ wt,
              float* __restrict__ out)
{
    __shared__ float  sx[CIN * SXR];    // 27904 B
    __shared__ float  sT[HLN];          //   432 B
    __shared__ ushort sop[NPX * 82];    // 10496 B (bf16 operator)
    __shared__ ushort zt[32 * ZROW];    // 37376 B (half-tile of pixels)
                                        // total 76208 B -> 2 blocks/CU

    const int tid  = threadIdx.x;
    const int lane = tid & 63;
    const int wv   = tid >> 6;
    const int b    = blockIdx.z;
    const int h0   = blockIdx.y * TH;
    const int w0   = blockIdx.x * TW;

    // ---- A-fragment preload (overlaps staging/T/MLP phases).
    // Wave wv owns o in [16*wv, 16*wv+16). k = s*32 + g*8 + i, linear k = kt*64+c.
    bf16x8 areg[18];
    {
        const ushort* ap = wt + (wv * 16 + (lane & 15)) * KTOT + ((lane >> 4) * 8);
        #pragma unroll
        for (int s = 0; s < 18; ++s)
            areg[s] = *reinterpret_cast<const bf16x8*>(ap + s * 32);
    }

    // ---- stage x tile + halo (zero-padded), row stride SXR ----
    const float* __restrict__ xb = x + (size_t)b * CIN * HW * HW;
    #pragma unroll
    for (int it = 0; it < 27; ++it) {              // 27*256 = 6912 = CIN*HLN
        int i  = tid + it * 256;
        int c  = i / HLN;
        int r  = i - c * HLN;
        int hy = r / HLW;
        int hx = r - hy * HLW;
        int gy = h0 - 1 + hy;
        int gx = w0 - 1 + hx;
        float v = 0.f;
        if ((unsigned)gy < HW && (unsigned)gx < HW)
            v = xb[c * HW * HW + gy * HW + gx];
        sx[c * SXR + r] = v;
    }
    __syncthreads();

    // ---- T: per-position channel square-sum ----
    if (tid < HLN) {
        float s = 0.f;
        #pragma unroll 16
        for (int c = 0; c < CIN; ++c) { float v = sx[c * SXR + tid]; s += v * v; }
        sT[tid] = s;
    }
    __syncthreads();

    // ---- per-pixel norms + dynamic operator -> sop (bf16) ----
    {
        const int px  = tid >> 2;                  // 0..63
        const int q   = tid & 3;
        const int py  = px >> 4, pxx = px & 15;
        float nrm[9];
        #pragma unroll
        for (int j = 0; j < 9; ++j)
            nrm[j] = sqrtf(sT[(py + j / 3) * HLW + pxx + (j % 3)]);
        const int m0   = q * 20;
        const int mcnt = (q == 3) ? 21 : 20;
        for (int mm = 0; mm < mcnt; ++mm) {
            int m = m0 + mm;
            float a = op_b[m];
            #pragma unroll
            for (int j = 0; j < 9; ++j) a += nrm[j] * op_w[m * 9 + j];
            sop[px * 82 + m] = f32_to_bf16_rne(tanhf(a));
        }
    }
    __syncthreads();

    // ---- two half-tiles: Z (VALU) then MFMA, zt reused ----
    #pragma unroll 1
    for (int hh = 0; hh < 2; ++hh) {
        // -- Z phase: 32 px, 8 threads/px, 8 channels/thread --
        {
            const int pxl = tid >> 3;              // 0..31 local pixel
            const int px  = hh * 32 + pxl;
            const int cq  = tid & 7;
            const int py  = px >> 4, pxx = px & 15;

            float xu[8][9];
            #pragma unroll
            for (int cc = 0; cc < 8; ++cc) {
                const int base = (cq * 8 + cc) * SXR;
                #pragma unroll
                for (int j = 0; j < 9; ++j)
                    xu[cc][j] = sx[base + (py + j / 3) * HLW + pxx + (j % 3)];
            }
            #pragma unroll
            for (int k = 0; k < 9; ++k) {
                float opj[9];
                #pragma unroll
                for (int j = 0; j < 9; ++j)
                    opj[j] = bf16u_to_f32(sop[px * 82 + j * 9 + k]);
                float y[8];
                #pragma unroll
                for (int cc = 0; cc < 8; ++cc) {
                    float s = xu[cc][k];
                    #pragma unroll
                    for (int j = 0; j < 9; ++j) s += xu[cc][j] * opj[j];
                    y[cc] = s;
                }
                uint32_t p0, p1, p2, p3;
                asm("v_cvt_pk_bf16_f32 %0, %1, %2" : "=v"(p0) : "v"(y[0]), "v"(y[1]));
                asm("v_cvt_pk_bf16_f32 %0, %1, %2" : "=v"(p1) : "v"(y[2]), "v"(y[3]));
                asm("v_cvt_pk_bf16_f32 %0, %1, %2" : "=v"(p2) : "v"(y[4]), "v"(y[5]));
                asm("v_cvt_pk_bf16_f32 %0, %1, %2" : "=v"(p3) : "v"(y[6]), "v"(y[7]));
                *reinterpret_cast<uint4*>(&zt[pxl * ZROW + k * 64 + cq * 8])
                    = make_uint4(p0, p1, p2, p3);
            }
        }
        __syncthreads();

        // -- MFMA: out[o, px] for the 32 px of this half --
        {
            f32x4 acc[2];
            acc[0] = f32x4{0.f, 0.f, 0.f, 0.f};
            acc[1] = f32x4{0.f, 0.f, 0.f, 0.f};
            const int bl = lane & 15;
            const int g8 = (lane >> 4) * 8;
            #pragma unroll
            for (int s = 0; s < 18; ++s) {
                #pragma unroll
                for (int nf = 0; nf < 2; ++nf) {
                    const ushort* bp = &zt[(nf * 16 + bl) * ZROW + s * 32 + g8];
                    bf16x8 bfr = *reinterpret_cast<const bf16x8*>(bp);
                    acc[nf] = __builtin_amdgcn_mfma_f32_16x16x32_bf16(areg[s], bfr, acc[nf], 0, 0, 0);
                }
            }
            // D: row m = o = wv*16 + (lane>>4)*4 + i ; col n = px = (hh*2+nf)*16 + bl
            #pragma unroll
            for (int nf = 0; nf < 2; ++nf) {
                const int py = hh * 2 + nf;
                #pragma unroll
                for (int i = 0; i < 4; ++i) {
                    const int o = wv * 16 + (lane >> 4) * 4 + i;
                    out[(((size_t)b * OC + o) * HW + (h0 + py)) * HW + w0 + bl]
                        = acc[nf][i] + bias[o];
                }
            }
        }
        __syncthreads();   // zt safe to overwrite (also paired for hh=1)
    }
}

extern "C" void kernel_launch(void* const* d_in, const int* in_sizes, int n_in,
                              void* d_out, int out_size, void* d_ws, size_t ws_size,
                              hipStream_t stream) {
    const float* x      = (const float*)d_in[0];
    const float* weight = (const float*)d_in[1];
    const float* bias   = (const float*)d_in[2];
    const float* op_w   = (const float*)d_in[3];
    const float* op_b   = (const float*)d_in[4];
    float*  out = (float*)d_out;
    ushort* wt  = (ushort*)d_ws;                   // 73728 B

    prep_weight<<<dim3((OC * KTOT) / 256), dim3(256), 0, stream>>>(weight, wt);

    dim3 grid(HW / TW, HW / TH, 8);                // 2048 blocks
    dyf_main<<<grid, dim3(256), 0, stream>>>(x, bias, op_w, op_b, wt, out);
}